// Round 1
// baseline (1050.744 us; speedup 1.0000x reference)
//
#include <hip/hip_runtime.h>
#include <hip/hip_bf16.h>
#include <hip/hip_fp16.h>

// Problem constants
#define NB 8
#define NT 1024
#define MD 1024
#define SD 256
#define NSTATES 16
#define NTOK (NB*NT)            // 8192
#define OUT_MAIN (NTOK*MD)      // 8388608

typedef __attribute__((ext_vector_type(8))) short bf16x8;
typedef __attribute__((ext_vector_type(4))) float f32x4;
typedef _Float16 f16x2 __attribute__((ext_vector_type(2)));

#if defined(__has_builtin)
#if __has_builtin(__builtin_amdgcn_fdot2)
#define HAVE_FDOT2 1
#endif
#endif

static __device__ __forceinline__ unsigned short f32_to_bf16_bits(float f) {
    union { float f; unsigned u; } v; v.f = f;
    unsigned r = v.u + 0x7FFFu + ((v.u >> 16) & 1u);
    return (unsigned short)(r >> 16);
}

// ---------------------------------------------------------------------------
// K1: out = base (exact f32 copy), zero accumulators (ent_sum f32, count u32)
// grid 2048 x 256; each thread copies 4 float4
__global__ void k_copy_zero(const float4* __restrict__ base, float4* __restrict__ out,
                            float* __restrict__ accums) {
    unsigned i = blockIdx.x * 256u + threadIdx.x;
    const unsigned STRIDE = 524288u; // total float4 = 2097152
#pragma unroll
    for (int q = 0; q < 4; q++) out[i + q * STRIDE] = base[i + q * STRIDE];
    if (i == 0u) { accums[0] = 0.f; ((unsigned*)accums)[1] = 0u; }
}

// ---------------------------------------------------------------------------
// K2: prep weights + active list.
//  - Bt[512][1024] bf16 : row n = column n of [Wsi|Wgi]  (N-major, K contiguous)
//  - Wrec[(kh*64+p)*512 + j] : packed f16x2 = (Wcat[k][j], Wcat[k+1][j]), k=kh*128+2p
//    where Wcat col j<256 -> Wsh col j ; j>=256 -> Wgh col j-256
//  - active list: (tok<<6)|slot appended with atomic counter
__global__ void k_prep(const float* __restrict__ Wsi, const float* __restrict__ Wgi,
                       const float* __restrict__ Wsh, const float* __restrict__ Wgh,
                       const int* __restrict__ ids, const int* __restrict__ t2s,
                       unsigned short* __restrict__ Bt, unsigned* __restrict__ Wrec,
                       unsigned* __restrict__ list, unsigned* __restrict__ countp) {
    unsigned i = blockIdx.x * 256u + threadIdx.x;
    if (i < 524288u) {
        unsigned n = i >> 10, k = i & 1023u;
        float v = (n < 256u) ? Wsi[k * 256u + n] : Wgi[k * 256u + (n - 256u)];
        Bt[i] = f32_to_bf16_bits(v);
    } else if (i < 589824u) {
        unsigned w = i - 524288u;
        unsigned j = w & 511u;
        unsigned pq = w >> 9;           // 0..127
        unsigned p = pq & 63u, kh = pq >> 6;
        unsigned k = kh * 128u + 2u * p;
        float v0, v1;
        if (j < 256u) { v0 = Wsh[k * 256u + j];          v1 = Wsh[(k + 1u) * 256u + j]; }
        else          { v0 = Wgh[k * 256u + (j - 256u)]; v1 = Wgh[(k + 1u) * 256u + (j - 256u)]; }
        union { _Float16 h[2]; unsigned u; } pk;
        pk.h[0] = (_Float16)v0; pk.h[1] = (_Float16)v1;
        Wrec[w] = pk.u;
    } else if (i < 598016u) {
        unsigned tok = i - 589824u;
        int slot = t2s[ids[tok]];
        if (slot >= 0) {
            unsigned pos = atomicAdd(countp, 1u);
            list[pos] = (tok << 6) | (unsigned)slot;
        }
    }
}

// ---------------------------------------------------------------------------
// K3: XW[8192][512] f32 = bf16(base[8192][1024]) @ [Wsi|Wgi]
// 128(M)x256(N) tile, BK=32, 512 threads = 8 waves (2M x 4N), wave tile 64x64,
// 4x4 fragments of mfma_f32_16x16x32_bf16. LDS rows padded to 40 elems (80 B,
// 16B-aligned, row-part bank stride 20 -> 2-way only).
__launch_bounds__(512, 1)
__global__ void k_gemm(const float* __restrict__ A, const unsigned short* __restrict__ Bt,
                       float* __restrict__ XW) {
    __shared__ __align__(16) unsigned short Abuf[128 * 40];
    __shared__ __align__(16) unsigned short Bbuf[256 * 40];
    const unsigned tid = threadIdx.x;
    const unsigned m0 = blockIdx.x * 128u;
    const unsigned n0 = blockIdx.y * 256u;
    const unsigned wave = tid >> 6, lane = tid & 63u;
    const unsigned wm = wave >> 2, wn = wave & 3u;
    const unsigned l15 = lane & 15u, kg = lane >> 4;
    const unsigned ar = tid >> 2;           // 0..127
    const unsigned ac = (tid & 3u) * 8u;    // 0,8,16,24

    f32x4 acc[4][4];
#pragma unroll
    for (int i = 0; i < 4; i++)
#pragma unroll
        for (int j = 0; j < 4; j++) acc[i][j] = (f32x4){0.f, 0.f, 0.f, 0.f};

    for (unsigned k0 = 0; k0 < 1024u; k0 += 32u) {
        { // stage A (f32 -> bf16)
            const float* src = A + (size_t)(m0 + ar) * 1024u + k0 + ac;
            float4 f0 = *(const float4*)src;
            float4 f1 = *(const float4*)(src + 4);
            unsigned short* dst = &Abuf[ar * 40u + ac];
            dst[0] = f32_to_bf16_bits(f0.x); dst[1] = f32_to_bf16_bits(f0.y);
            dst[2] = f32_to_bf16_bits(f0.z); dst[3] = f32_to_bf16_bits(f0.w);
            dst[4] = f32_to_bf16_bits(f1.x); dst[5] = f32_to_bf16_bits(f1.y);
            dst[6] = f32_to_bf16_bits(f1.z); dst[7] = f32_to_bf16_bits(f1.w);
        }
#pragma unroll
        for (int q = 0; q < 2; q++) { // stage B (already bf16)
            unsigned br = q * 128u + (tid >> 2);
            const unsigned short* src = Bt + (size_t)(n0 + br) * 1024u + k0 + ac;
            *(uint4*)&Bbuf[br * 40u + ac] = *(const uint4*)src;
        }
        __syncthreads();
        bf16x8 a[4], b[4];
#pragma unroll
        for (int i = 0; i < 4; i++)
            a[i] = *(const bf16x8*)&Abuf[(wm * 64u + i * 16u + l15) * 40u + kg * 8u];
#pragma unroll
        for (int j = 0; j < 4; j++)
            b[j] = *(const bf16x8*)&Bbuf[(wn * 64u + j * 16u + l15) * 40u + kg * 8u];
#pragma unroll
        for (int i = 0; i < 4; i++)
#pragma unroll
            for (int j = 0; j < 4; j++)
                acc[i][j] = __builtin_amdgcn_mfma_f32_16x16x32_bf16(a[i], b[j], acc[i][j], 0, 0, 0);
        __syncthreads();
    }
    // epilogue: C layout col = lane&15, row = (lane>>4)*4 + reg
#pragma unroll
    for (int i = 0; i < 4; i++) {
        unsigned row_b = m0 + wm * 64u + i * 16u + kg * 4u;
#pragma unroll
        for (int j = 0; j < 4; j++) {
            unsigned col = n0 + wn * 64u + j * 16u + l15;
#pragma unroll
            for (int r = 0; r < 4; r++)
                XW[(size_t)(row_b + r) * 512u + col] = acc[i][j][r];
        }
    }
}

// ---------------------------------------------------------------------------
// K4: sequential GRU recurrence. One WG per batch, 1024 threads.
// thread = (j in [0,512), kh in {0,1}). Owns output column j, K-half kh.
// Weights resident: 64 packed-f16 pairs (64 VGPRs). h broadcast from LDS.
__launch_bounds__(1024, 1)
__global__ void k_rec(const float* __restrict__ XW, const unsigned* __restrict__ Wrec,
                      float* __restrict__ prefix) {
    __shared__ float hF32[256];
    __shared__ __align__(16) unsigned short hHalf[256]; // f16 bits of h
    __shared__ float part[512];
    __shared__ float sums[512];
    const unsigned tid = threadIdx.x;
    const unsigned j = tid & 511u, kh = tid >> 9;
    const unsigned b = blockIdx.x;

    unsigned wreg[64];
#pragma unroll
    for (int p = 0; p < 64; p++) wreg[p] = Wrec[((kh * 64u + p) << 9) + j];

    if (tid < 256u) hF32[tid] = 0.f;
    if (tid < 128u) ((unsigned*)hHalf)[tid] = 0u;
    __syncthreads();

    const float* xwb = XW + (size_t)b * 1024u * 512u;
    float* pfb = prefix + (size_t)b * 1024u * 256u;
    float xw_cur = (kh == 0u) ? xwb[j] : 0.f;

    for (unsigned t = 0; t < 1024u; ++t) {
        float xw_next = 0.f;
        if (kh == 0u && t < 1023u) xw_next = xwb[(t + 1u) * 512u + j];

        float acc = 0.f;
        const uint4* hp = (const uint4*)(((const unsigned*)hHalf) + kh * 64u);
#pragma unroll
        for (int p = 0; p < 16; p++) {
            uint4 h4 = hp[p];
#ifdef HAVE_FDOT2
            acc = __builtin_amdgcn_fdot2(__builtin_bit_cast(f16x2, h4.x), __builtin_bit_cast(f16x2, wreg[4*p+0]), acc, false);
            acc = __builtin_amdgcn_fdot2(__builtin_bit_cast(f16x2, h4.y), __builtin_bit_cast(f16x2, wreg[4*p+1]), acc, false);
            acc = __builtin_amdgcn_fdot2(__builtin_bit_cast(f16x2, h4.z), __builtin_bit_cast(f16x2, wreg[4*p+2]), acc, false);
            acc = __builtin_amdgcn_fdot2(__builtin_bit_cast(f16x2, h4.w), __builtin_bit_cast(f16x2, wreg[4*p+3]), acc, false);
#else
            {
                f16x2 hv, wv;
                hv = __builtin_bit_cast(f16x2, h4.x); wv = __builtin_bit_cast(f16x2, wreg[4*p+0]);
                acc += (float)hv.x * (float)wv.x + (float)hv.y * (float)wv.y;
                hv = __builtin_bit_cast(f16x2, h4.y); wv = __builtin_bit_cast(f16x2, wreg[4*p+1]);
                acc += (float)hv.x * (float)wv.x + (float)hv.y * (float)wv.y;
                hv = __builtin_bit_cast(f16x2, h4.z); wv = __builtin_bit_cast(f16x2, wreg[4*p+2]);
                acc += (float)hv.x * (float)wv.x + (float)hv.y * (float)wv.y;
                hv = __builtin_bit_cast(f16x2, h4.w); wv = __builtin_bit_cast(f16x2, wreg[4*p+3]);
                acc += (float)hv.x * (float)wv.x + (float)hv.y * (float)wv.y;
            }
#endif
        }
        if (kh) part[j] = acc; else sums[j] = acc + xw_cur;
        __syncthreads();
        if (tid < 256u) {
            float s = sums[tid] + part[tid];
            float g = sums[tid + 256u] + part[tid + 256u];
            float gate = 1.f / (1.f + expf(-g));
            float prop = tanhf(s);
            float hold = hF32[tid];
            float hnew = gate * prop + (1.f - gate) * hold;
            pfb[t * 256u + tid] = hold;        // prefix = state BEFORE update
            hF32[tid] = hnew;
            union { _Float16 h; unsigned short u; } cv; cv.h = (_Float16)hnew;
            hHalf[tid] = cv.u;
        }
        __syncthreads();
        xw_cur = xw_next;
    }
}

// ---------------------------------------------------------------------------
// K5: router + delta mix at active tokens only. grid-stride over device count.
__launch_bounds__(256, 1)
__global__ void k_router(const unsigned* __restrict__ list, const float* __restrict__ accums_ro,
                         const float* __restrict__ prefix, const float* __restrict__ base,
                         const float* __restrict__ Wrh, const float* __restrict__ Wro,
                         const float* __restrict__ delta, float* __restrict__ out,
                         float* __restrict__ ent_sum) {
    const unsigned cnt = ((const unsigned*)accums_ro)[1];
    __shared__ float f[1280];
    __shared__ float hid[256];
    __shared__ float pr[16];
    const unsigned tid = threadIdx.x;
    for (unsigned idx = blockIdx.x; idx < cnt; idx += gridDim.x) {
        unsigned e = list[idx];
        unsigned tok = e >> 6, slot = e & 63u;
        // feats = [prefix(256) | base(1024)]
        f[tid] = prefix[(size_t)tok * 256u + tid];
#pragma unroll
        for (int q = 0; q < 4; q++)
            f[256u + q * 256u + tid] = base[(size_t)tok * 1024u + q * 256u + tid];
        __syncthreads();
        float a = 0.f;
        for (unsigned k = 0; k < 1280u; k++) a += f[k] * Wrh[k * 256u + tid];
        hid[tid] = tanhf(a);
        __syncthreads();
        if (tid < 16u) {
            float l = 0.f;
            for (unsigned k = 0; k < 256u; k++) l += hid[k] * Wro[k * 16u + tid];
            pr[tid] = l;
        }
        __syncthreads();
        if (tid == 0u) {
            float m = pr[0];
#pragma unroll
            for (int n = 1; n < 16; n++) m = fmaxf(m, pr[n]);
            float es[16]; float ssum = 0.f;
#pragma unroll
            for (int n = 0; n < 16; n++) { es[n] = expf(pr[n] - m); ssum += es[n]; }
            float inv = 1.f / ssum, ent = 0.f;
#pragma unroll
            for (int n = 0; n < 16; n++) {
                float p = es[n] * inv;
                pr[n] = p;
                ent -= p * logf(fmaxf(p, 1e-8f));
            }
            atomicAdd(ent_sum, ent);
        }
        __syncthreads();
        { // mixed delta add: out[tok] += 0.25 * sum_n probs[n] * delta[slot][n][:]
            const float* dslot = delta + (size_t)slot * 16u * 1024u;
            unsigned d0 = tid * 4u;
            float4 m4 = {0.f, 0.f, 0.f, 0.f};
#pragma unroll
            for (int n = 0; n < 16; n++) {
                float p = pr[n];
                float4 dv = *(const float4*)(dslot + n * 1024u + d0);
                m4.x += p * dv.x; m4.y += p * dv.y; m4.z += p * dv.z; m4.w += p * dv.w;
            }
            float* op = out + (size_t)tok * 1024u + d0;
            float4 cur = *(const float4*)op;
            cur.x += 0.25f * m4.x; cur.y += 0.25f * m4.y;
            cur.z += 0.25f * m4.z; cur.w += 0.25f * m4.w;
            *(float4*)op = cur;
        }
        __syncthreads();
    }
}

// ---------------------------------------------------------------------------
// K6: scalars
__global__ void k_final(const float* __restrict__ accums, float* __restrict__ out) {
    float ent = accums[0];
    unsigned cnt = ((const unsigned*)accums)[1];
    out[OUT_MAIN]     = (cnt > 0u) ? ent / (float)cnt : 0.f;
    out[OUT_MAIN + 1] = (float)cnt / 8192.f;
}

// ---------------------------------------------------------------------------
extern "C" void kernel_launch(void* const* d_in, const int* in_sizes, int n_in,
                              void* d_out, int out_size, void* d_ws, size_t ws_size,
                              hipStream_t stream) {
    const int*   ids  = (const int*)d_in[0];
    const float* base = (const float*)d_in[1];
    const int*   t2s  = (const int*)d_in[2];
    const float* Wsi  = (const float*)d_in[3];
    const float* Wsh  = (const float*)d_in[4];
    const float* Wgi  = (const float*)d_in[5];
    const float* Wgh  = (const float*)d_in[6];
    const float* Wrh  = (const float*)d_in[7];
    const float* Wro  = (const float*)d_in[8];
    const float* delta = (const float*)d_in[9];
    float* out = (float*)d_out;

    char* ws = (char*)d_ws;
    float*          XW     = (float*)(ws);                      // 16,777,216 B
    float*          prefix = (float*)(ws + 16777216);           //  8,388,608 B
    unsigned short* Bt     = (unsigned short*)(ws + 25165824);  //  1,048,576 B
    unsigned*       Wrec   = (unsigned*)(ws + 26214400);        //    262,144 B
    unsigned*       list   = (unsigned*)(ws + 26476544);        //     32,768 B
    float*          accums = (float*)(ws + 26509312);           //          8 B

    hipLaunchKernelGGL(k_copy_zero, dim3(2048), dim3(256), 0, stream,
                       (const float4*)base, (float4*)out, accums);
    hipLaunchKernelGGL(k_prep, dim3(2336), dim3(256), 0, stream,
                       Wsi, Wgi, Wsh, Wgh, ids, t2s, Bt, Wrec, list,
                       (unsigned*)accums + 1);
    hipLaunchKernelGGL(k_gemm, dim3(64, 2), dim3(512), 0, stream, base, Bt, XW);
    hipLaunchKernelGGL(k_rec, dim3(8), dim3(1024), 0, stream, XW, Wrec, prefix);
    hipLaunchKernelGGL(k_router, dim3(64), dim3(256), 0, stream,
                       list, accums, prefix, base, Wrh, Wro, delta, out, accums);
    hipLaunchKernelGGL(k_final, dim3(1), dim3(1), 0, stream, accums, out);
}

// Round 2
// 1008.909 us; speedup vs baseline: 1.0415x; 1.0415x over previous
//
#include <hip/hip_runtime.h>
#include <hip/hip_bf16.h>
#include <hip/hip_fp16.h>

// Problem constants
#define NB 8
#define NT 1024
#define MD 1024
#define SD 256
#define NSTATES 16
#define NTOK (NB*NT)            // 8192
#define OUT_MAIN (NTOK*MD)      // 8388608

typedef __attribute__((ext_vector_type(8))) short bf16x8;
typedef __attribute__((ext_vector_type(4))) float f32x4;
typedef _Float16 f16x2 __attribute__((ext_vector_type(2)));

#if defined(__has_builtin)
#if __has_builtin(__builtin_amdgcn_fdot2)
#define HAVE_FDOT2 1
#endif
#endif

static __device__ __forceinline__ unsigned short f32_to_bf16_bits(float f) {
    union { float f; unsigned u; } v; v.f = f;
    unsigned r = v.u + 0x7FFFu + ((v.u >> 16) & 1u);
    return (unsigned short)(r >> 16);
}

static __device__ __forceinline__ float fdot2f(unsigned hbits, unsigned wbits, float acc) {
#ifdef HAVE_FDOT2
    return __builtin_amdgcn_fdot2(__builtin_bit_cast(f16x2, hbits),
                                  __builtin_bit_cast(f16x2, wbits), acc, false);
#else
    f16x2 hv = __builtin_bit_cast(f16x2, hbits), wv = __builtin_bit_cast(f16x2, wbits);
    return acc + (float)hv.x * (float)wv.x + (float)hv.y * (float)wv.y;
#endif
}

static __device__ __forceinline__ float fast_exp2(float x) {
#if __has_builtin(__builtin_amdgcn_exp2f)
    return __builtin_amdgcn_exp2f(x);
#else
    return exp2f(x);
#endif
}
static __device__ __forceinline__ float fast_rcp(float x) {
#if __has_builtin(__builtin_amdgcn_rcpf)
    return __builtin_amdgcn_rcpf(x);
#else
    return 1.f / x;
#endif
}

// async global(16B/lane) -> LDS (wave-uniform base, lane*16 stride)
static __device__ __forceinline__ void gld16(const void* g, void* l) {
    __builtin_amdgcn_global_load_lds(
        (const __attribute__((address_space(1))) void*)g,
        (__attribute__((address_space(3))) void*)l, 16, 0, 0);
}

#define STEP_BARRIER() do { \
    asm volatile("s_waitcnt lgkmcnt(0)" ::: "memory"); \
    __builtin_amdgcn_s_barrier(); \
    asm volatile("" ::: "memory"); } while (0)

#define CHUNK_BARRIER() do { \
    asm volatile("s_waitcnt vmcnt(0) lgkmcnt(0)" ::: "memory"); \
    __builtin_amdgcn_s_barrier(); \
    asm volatile("" ::: "memory"); } while (0)

// ---------------------------------------------------------------------------
// K1: out = base (exact f32 copy), zero accumulators (ent_sum f32, count u32)
__global__ void k_copy_zero(const float4* __restrict__ base, float4* __restrict__ out,
                            float* __restrict__ accums) {
    unsigned i = blockIdx.x * 256u + threadIdx.x;
    const unsigned STRIDE = 524288u; // total float4 = 2097152
#pragma unroll
    for (int q = 0; q < 4; q++) out[i + q * STRIDE] = base[i + q * STRIDE];
    if (i == 0u) { accums[0] = 0.f; ((unsigned*)accums)[1] = 0u; }
}

// ---------------------------------------------------------------------------
// K2: prep weights + active list.
//  - Bt[512][1024] bf16 : row n = column n of [Wsi|Wgi]
//  - WsP/WgP[p*512 + (2j+kh)] : f16x2 pack of Wsh/Wgh[(kh*128+2p)..+1][j]
//  - active list: (tok<<6)|slot appended with atomic counter
__global__ void k_prep(const float* __restrict__ Wsi, const float* __restrict__ Wgi,
                       const float* __restrict__ Wsh, const float* __restrict__ Wgh,
                       const int* __restrict__ ids, const int* __restrict__ t2s,
                       unsigned short* __restrict__ Bt,
                       unsigned* __restrict__ WsP, unsigned* __restrict__ WgP,
                       unsigned* __restrict__ list, unsigned* __restrict__ countp) {
    unsigned i = blockIdx.x * 256u + threadIdx.x;
    if (i < 524288u) {
        unsigned n = i >> 10, k = i & 1023u;
        float v = (n < 256u) ? Wsi[k * 256u + n] : Wgi[k * 256u + (n - 256u)];
        Bt[i] = f32_to_bf16_bits(v);
    } else if (i < 589824u) {
        unsigned w = i - 524288u;          // 0..65535 : first half WsP, second WgP
        const float* W = (w < 32768u) ? Wsh : Wgh;
        unsigned*    D = (w < 32768u) ? WsP : WgP;
        unsigned ww = w & 32767u;
        unsigned p = ww >> 9, r = ww & 511u, jj = r >> 1, kh = r & 1u;
        unsigned k = kh * 128u + 2u * p;
        union { _Float16 h[2]; unsigned u; } pk;
        pk.h[0] = (_Float16)W[k * 256u + jj];
        pk.h[1] = (_Float16)W[(k + 1u) * 256u + jj];
        D[ww] = pk.u;
    } else if (i < 598016u) {
        unsigned tok = i - 589824u;
        int slot = t2s[ids[tok]];
        if (slot >= 0) {
            unsigned pos = atomicAdd(countp, 1u);
            list[pos] = (tok << 6) | (unsigned)slot;
        }
    }
}

// ---------------------------------------------------------------------------
// K3: XW[8192][512] f32 = bf16(base) @ [Wsi|Wgi]  (unchanged from r1)
__launch_bounds__(512, 1)
__global__ void k_gemm(const float* __restrict__ A, const unsigned short* __restrict__ Bt,
                       float* __restrict__ XW) {
    __shared__ __align__(16) unsigned short Abuf[128 * 40];
    __shared__ __align__(16) unsigned short Bbuf[256 * 40];
    const unsigned tid = threadIdx.x;
    const unsigned m0 = blockIdx.x * 128u;
    const unsigned n0 = blockIdx.y * 256u;
    const unsigned wave = tid >> 6, lane = tid & 63u;
    const unsigned wm = wave >> 2, wn = wave & 3u;
    const unsigned l15 = lane & 15u, kg = lane >> 4;
    const unsigned ar = tid >> 2;
    const unsigned ac = (tid & 3u) * 8u;

    f32x4 acc[4][4];
#pragma unroll
    for (int i = 0; i < 4; i++)
#pragma unroll
        for (int j = 0; j < 4; j++) acc[i][j] = (f32x4){0.f, 0.f, 0.f, 0.f};

    for (unsigned k0 = 0; k0 < 1024u; k0 += 32u) {
        {
            const float* src = A + (size_t)(m0 + ar) * 1024u + k0 + ac;
            float4 f0 = *(const float4*)src;
            float4 f1 = *(const float4*)(src + 4);
            unsigned short* dst = &Abuf[ar * 40u + ac];
            dst[0] = f32_to_bf16_bits(f0.x); dst[1] = f32_to_bf16_bits(f0.y);
            dst[2] = f32_to_bf16_bits(f0.z); dst[3] = f32_to_bf16_bits(f0.w);
            dst[4] = f32_to_bf16_bits(f1.x); dst[5] = f32_to_bf16_bits(f1.y);
            dst[6] = f32_to_bf16_bits(f1.z); dst[7] = f32_to_bf16_bits(f1.w);
        }
#pragma unroll
        for (int q = 0; q < 2; q++) {
            unsigned br = q * 128u + (tid >> 2);
            const unsigned short* src = Bt + (size_t)(n0 + br) * 1024u + k0 + ac;
            *(uint4*)&Bbuf[br * 40u + ac] = *(const uint4*)src;
        }
        __syncthreads();
        bf16x8 a[4], b[4];
#pragma unroll
        for (int i = 0; i < 4; i++)
            a[i] = *(const bf16x8*)&Abuf[(wm * 64u + i * 16u + l15) * 40u + kg * 8u];
#pragma unroll
        for (int j = 0; j < 4; j++)
            b[j] = *(const bf16x8*)&Bbuf[(wn * 64u + j * 16u + l15) * 40u + kg * 8u];
#pragma unroll
        for (int i = 0; i < 4; i++)
#pragma unroll
            for (int j = 0; j < 4; j++)
                acc[i][j] = __builtin_amdgcn_mfma_f32_16x16x32_bf16(a[i], b[j], acc[i][j], 0, 0, 0);
        __syncthreads();
    }
#pragma unroll
    for (int i = 0; i < 4; i++) {
        unsigned row_b = m0 + wm * 64u + i * 16u + kg * 4u;
#pragma unroll
        for (int j = 0; j < 4; j++) {
            unsigned col = n0 + wn * 64u + j * 16u + l15;
#pragma unroll
            for (int r = 0; r < 4; r++)
                XW[(size_t)(row_b + r) * 512u + col] = acc[i][j][r];
        }
    }
}

// ---------------------------------------------------------------------------
// K4: sequential GRU recurrence, v2.
// One WG per batch, 512 threads (8 waves). Lane pair (2j, 2j+1) owns output
// index j: lane kh computes K-half kh of BOTH proposal col j and gate col j.
// Cross-pair reduce via __shfl_xor(.,1) (in-wave). h double-buffered in LDS
// (f16) -> ONE raw barrier per step (no vmcnt drain: prefix stores and
// async XW chunk loads stay in flight). XW staged in 16-step LDS chunks via
// global_load_lds, issued one chunk ahead, waited once per chunk.
__launch_bounds__(512, 2)
__global__ void k_rec(const float* __restrict__ XW,
                      const unsigned* __restrict__ WsP, const unsigned* __restrict__ WgP,
                      float* __restrict__ prefix) {
    __shared__ __align__(16) unsigned short hH[2][256];
    __shared__ __align__(16) float xwC[2][16 * 512];
    const unsigned tid = threadIdx.x;
    const unsigned j = tid >> 1, kh = tid & 1u;
    const unsigned wv = tid >> 6;            // wave id (uniform in wave)
    const unsigned lane = tid & 63u;
    const unsigned b = blockIdx.x;

    // register-resident weights: 64 f16x2 for proposal + 64 for gate
    unsigned ws[64], wg[64];
#pragma unroll
    for (int p = 0; p < 64; p++) ws[p] = WsP[(p << 9) + tid];
#pragma unroll
    for (int p = 0; p < 64; p++) wg[p] = WgP[(p << 9) + tid];

    const float* xwb = XW + (size_t)b * (1024u * 512u);
    float* pfb = prefix + (size_t)b * (1024u * 256u);

    if (tid < 32u) ((uint4*)&hH[0][0])[tid] = (uint4){0u, 0u, 0u, 0u};

    // issue chunk c (16 steps = 8192 floats) into xwC[c&1]
    auto issue_chunk = [&](unsigned c) {
#pragma unroll
        for (int q = 0; q < 2; q++) {
            unsigned off = (wv * 2u + q) * 256u;   // float offset, wave-uniform
            gld16(xwb + (size_t)c * 8192u + off + lane * 4u, &xwC[c & 1u][off]);
        }
    };
    issue_chunk(0u);

    const float L2E = 1.4426950408889634f;
    float hold = 0.f;
    unsigned t = 0;
    for (unsigned c = 0; c < 64u; ++c) {
        CHUNK_BARRIER();                 // xwC[c&1] ready everywhere
        if (c < 63u) issue_chunk(c + 1u);
        const float* xs = &xwC[c & 1u][0];
        for (unsigned s16 = 0; s16 < 16u; ++s16, ++t) {
            const uint4* hp = (const uint4*)&hH[t & 1u][kh << 7];
            float a0 = 0.f, a1 = 0.f, g0 = 0.f, g1 = 0.f;
#pragma unroll
            for (int q = 0; q < 16; q++) {
                uint4 h4 = hp[q];
                a0 = fdot2f(h4.x, ws[4 * q + 0], a0); g0 = fdot2f(h4.x, wg[4 * q + 0], g0);
                a1 = fdot2f(h4.y, ws[4 * q + 1], a1); g1 = fdot2f(h4.y, wg[4 * q + 1], g1);
                a0 = fdot2f(h4.z, ws[4 * q + 2], a0); g0 = fdot2f(h4.z, wg[4 * q + 2], g0);
                a1 = fdot2f(h4.w, ws[4 * q + 3], a1); g1 = fdot2f(h4.w, wg[4 * q + 3], g1);
            }
            float sp = a0 + a1, gp = g0 + g1;
            float sfull = sp + __shfl_xor(sp, 1) + xs[s16 * 512u + j];
            float gfull = gp + __shfl_xor(gp, 1) + xs[s16 * 512u + 256u + j];
            // sigmoid / tanh via v_exp_f32 + v_rcp_f32
            float gate = fast_rcp(1.f + fast_exp2(-gfull * L2E));
            float prop = 1.f - 2.f * fast_rcp(1.f + fast_exp2(2.f * L2E * sfull));
            float hnew = hold + gate * (prop - hold);
            if (!kh) {
                pfb[t * 256u + j] = hold;          // fire-and-forget (never drained)
                union { _Float16 h; unsigned short u; } cv; cv.h = (_Float16)hnew;
                hH[(t + 1u) & 1u][j] = cv.u;
            }
            hold = hnew;
            STEP_BARRIER();              // lgkmcnt only — vmem stays in flight
        }
    }
}

// ---------------------------------------------------------------------------
// K5: router + delta mix at active tokens only. grid-stride over device count.
__launch_bounds__(256, 1)
__global__ void k_router(const unsigned* __restrict__ list, const float* __restrict__ accums_ro,
                         const float* __restrict__ prefix, const float* __restrict__ base,
                         const float* __restrict__ Wrh, const float* __restrict__ Wro,
                         const float* __restrict__ delta, float* __restrict__ out,
                         float* __restrict__ ent_sum) {
    const unsigned cnt = ((const unsigned*)accums_ro)[1];
    __shared__ float f[1280];
    __shared__ float hid[256];
    __shared__ float pr[16];
    const unsigned tid = threadIdx.x;
    for (unsigned idx = blockIdx.x; idx < cnt; idx += gridDim.x) {
        unsigned e = list[idx];
        unsigned tok = e >> 6, slot = e & 63u;
        f[tid] = prefix[(size_t)tok * 256u + tid];
#pragma unroll
        for (int q = 0; q < 4; q++)
            f[256u + q * 256u + tid] = base[(size_t)tok * 1024u + q * 256u + tid];
        __syncthreads();
        float a = 0.f;
        for (unsigned k = 0; k < 1280u; k++) a += f[k] * Wrh[k * 256u + tid];
        hid[tid] = tanhf(a);
        __syncthreads();
        if (tid < 16u) {
            float l = 0.f;
            for (unsigned k = 0; k < 256u; k++) l += hid[k] * Wro[k * 16u + tid];
            pr[tid] = l;
        }
        __syncthreads();
        if (tid == 0u) {
            float m = pr[0];
#pragma unroll
            for (int n = 1; n < 16; n++) m = fmaxf(m, pr[n]);
            float es[16]; float ssum = 0.f;
#pragma unroll
            for (int n = 0; n < 16; n++) { es[n] = expf(pr[n] - m); ssum += es[n]; }
            float inv = 1.f / ssum, ent = 0.f;
#pragma unroll
            for (int n = 0; n < 16; n++) {
                float p = es[n] * inv;
                pr[n] = p;
                ent -= p * logf(fmaxf(p, 1e-8f));
            }
            atomicAdd(ent_sum, ent);
        }
        __syncthreads();
        {
            const float* dslot = delta + (size_t)slot * 16u * 1024u;
            unsigned d0 = tid * 4u;
            float4 m4 = {0.f, 0.f, 0.f, 0.f};
#pragma unroll
            for (int n = 0; n < 16; n++) {
                float p = pr[n];
                float4 dv = *(const float4*)(dslot + n * 1024u + d0);
                m4.x += p * dv.x; m4.y += p * dv.y; m4.z += p * dv.z; m4.w += p * dv.w;
            }
            float* op = out + (size_t)tok * 1024u + d0;
            float4 cur = *(const float4*)op;
            cur.x += 0.25f * m4.x; cur.y += 0.25f * m4.y;
            cur.z += 0.25f * m4.z; cur.w += 0.25f * m4.w;
            *(float4*)op = cur;
        }
        __syncthreads();
    }
}

// ---------------------------------------------------------------------------
// K6: scalars
__global__ void k_final(const float* __restrict__ accums, float* __restrict__ out) {
    float ent = accums[0];
    unsigned cnt = ((const unsigned*)accums)[1];
    out[OUT_MAIN]     = (cnt > 0u) ? ent / (float)cnt : 0.f;
    out[OUT_MAIN + 1] = (float)cnt / 8192.f;
}

// ---------------------------------------------------------------------------
extern "C" void kernel_launch(void* const* d_in, const int* in_sizes, int n_in,
                              void* d_out, int out_size, void* d_ws, size_t ws_size,
                              hipStream_t stream) {
    const int*   ids  = (const int*)d_in[0];
    const float* base = (const float*)d_in[1];
    const int*   t2s  = (const int*)d_in[2];
    const float* Wsi  = (const float*)d_in[3];
    const float* Wsh  = (const float*)d_in[4];
    const float* Wgi  = (const float*)d_in[5];
    const float* Wgh  = (const float*)d_in[6];
    const float* Wrh  = (const float*)d_in[7];
    const float* Wro  = (const float*)d_in[8];
    const float* delta = (const float*)d_in[9];
    float* out = (float*)d_out;

    char* ws = (char*)d_ws;
    float*          XW     = (float*)(ws);                      // 16,777,216 B
    float*          prefix = (float*)(ws + 16777216);           //  8,388,608 B
    unsigned short* Bt     = (unsigned short*)(ws + 25165824);  //  1,048,576 B
    unsigned*       WsP    = (unsigned*)(ws + 26214400);        //    131,072 B
    unsigned*       WgP    = (unsigned*)(ws + 26345472);        //    131,072 B
    unsigned*       list   = (unsigned*)(ws + 26476544);        //     32,768 B
    float*          accums = (float*)(ws + 26509312);           //          8 B

    hipLaunchKernelGGL(k_copy_zero, dim3(2048), dim3(256), 0, stream,
                       (const float4*)base, (float4*)out, accums);
    hipLaunchKernelGGL(k_prep, dim3(2336), dim3(256), 0, stream,
                       Wsi, Wgi, Wsh, Wgh, ids, t2s, Bt, WsP, WgP, list,
                       (unsigned*)accums + 1);
    hipLaunchKernelGGL(k_gemm, dim3(64, 2), dim3(512), 0, stream, base, Bt, XW);
    hipLaunchKernelGGL(k_rec, dim3(8), dim3(512), 0, stream, XW, WsP, WgP, prefix);
    hipLaunchKernelGGL(k_router, dim3(64), dim3(256), 0, stream,
                       list, accums, prefix, base, Wrh, Wro, delta, out, accums);
    hipLaunchKernelGGL(k_final, dim3(1), dim3(1), 0, stream, accums, out);
}